// Round 6
// baseline (199.484 us; speedup 1.0000x reference)
//
#include <hip/hip_runtime.h>

#define DEV __device__ __forceinline__

typedef __attribute__((ext_vector_type(8))) short short8v;
typedef __attribute__((ext_vector_type(4))) float f32x4;

DEV unsigned short bfr(float f) {                 // fp32 -> bf16 RNE (weights)
    unsigned u = __float_as_uint(f);
    return (unsigned short)((u + 0x7fffu + ((u >> 16) & 1u)) >> 16);
}
DEV short bft(float f) { return (short)(__float_as_uint(f) >> 16); } // truncate (activations)
DEV float bf2f(unsigned short h) { return __uint_as_float(((unsigned)h) << 16); }
DEV float frcp(float x) { return __builtin_amdgcn_rcpf(x); }
DEV float ftanh(float x) { float e = __expf(2.0f * x); return 1.0f - 2.0f * frcp(e + 1.0f); }

constexpr int NN = 4096, TT = 128;
#define MFMA32(a, b, c) __builtin_amdgcn_mfma_f32_16x16x32_bf16(a, b, c, 0, 0, 0)

// In-lane MFMA chaining with the VERIFIED 16x16x32 layout only:
// B slot k = quad*8+jj; we DEFINE feature(k) = (jj>>2)*16 + quad*4 + (jj&3).
// Then D (row = quad*4+reg) repacks into the next B operand fully in-lane
// (slot jj = h*4+reg), and all weight A-fragments are built with the same
// permuted k-order (free: arbitrary global indexing at build time).
// A operand: lane(quad,col) holds A[m=col][k=quad*8+jj].

// chunked scan over T, full/cheap cost ratio ~3
__constant__ const int CH_S[8] = {0, 44, 74, 94, 107, 116, 122, 126};
__constant__ const int CH_L[8] = {44, 30, 20, 13, 9, 6, 4, 2};

__global__ __attribute__((amdgpu_flat_work_group_size(512, 512), amdgpu_waves_per_eu(2, 2)))
void wfa_kernel(
    const float* __restrict__ x,
    const float* __restrict__ e1w, const float* __restrict__ e1b,
    const float* __restrict__ e2w, const float* __restrict__ e2b,
    const float* __restrict__ A,
    const float* __restrict__ initw,
    const float* __restrict__ n1w, const float* __restrict__ n1b,
    const float* __restrict__ n2w, const float* __restrict__ n2b,
    const float* __restrict__ muw, const float* __restrict__ mub,
    const float* __restrict__ sgw, const float* __restrict__ sgb,
    const float* __restrict__ alw, const float* __restrict__ alb,
    float* __restrict__ out)
{
    __shared__ __align__(16) unsigned short enc_l[TT * 128];  // [t][n*8+d] bf16
    __shared__ __align__(16) float x_l[16 * 130];             // [n][t]
    __shared__ __align__(16) float hs_l[8][16 * 68];          // enc-phase scratch only
    __shared__ float part_l[8][16];

    const int tid = threadIdx.x;
    const int wv = tid >> 6, lane = tid & 63;
    const int quad = lane >> 4, col = lane & 15;
    const int n0 = blockIdx.x * 16;
    const f32x4 z4 = {0.f, 0.f, 0.f, 0.f};

    // ---- stage x ----
    for (int i = tid; i < 16 * TT; i += 512)
        x_l[(i >> 7) * 130 + (i & 127)] = x[(n0 + (i >> 7)) * TT + (i & 127)];

    // permuted input-feature index for B/k-slot (kc grows K in 32-chunks)
    auto fi = [&](int kc, int jj) { return kc * 32 + (jj >> 2) * 16 + quad * 4 + (jj & 3); };

    // ---- persistent weight A-fragments (permuted k-order) ----
    short8v A2f[16];   // contraction: out m = mt*16+col -> d=mt>>1, j=(mt&1)*16+col; k=i
    #pragma unroll
    for (int mt = 0; mt < 16; ++mt)
        #pragma unroll
        for (int jj = 0; jj < 8; ++jj)
            A2f[mt][jj] = (short)bfr(A[fi(0, jj) * 256 + (mt >> 1) * 32 + (mt & 1) * 16 + col]);

    short8v W1f[4];    // h1 out = mt*16+col, k = th feature
    #pragma unroll
    for (int mt = 0; mt < 4; ++mt)
        #pragma unroll
        for (int jj = 0; jj < 8; ++jj)
            W1f[mt][jj] = (short)bfr(n1w[fi(0, jj) * 64 + mt * 16 + col]);

    short8v W2f[4][2]; // h2 out = mt*16+col, K=64 over kb
    #pragma unroll
    for (int mt = 0; mt < 4; ++mt)
        #pragma unroll
        for (int kb = 0; kb < 2; ++kb)
            #pragma unroll
            for (int jj = 0; jj < 8; ++jj)
                W2f[mt][kb][jj] = (short)bfr(n2w[fi(kb, jj) * 64 + mt * 16 + col]);

    short8v Whf[3][2]; // heads: mt 0=mu,1=sig,2=alpha; out m = head idx (col<10)
    #pragma unroll
    for (int mt = 0; mt < 3; ++mt) {
        const float* Wh = (mt == 0) ? muw : (mt == 1) ? sgw : alw;
        #pragma unroll
        for (int kb = 0; kb < 2; ++kb)
            #pragma unroll
            for (int jj = 0; jj < 8; ++jj)
                Whf[mt][kb][jj] = (short)bfr(col < 10 ? Wh[fi(kb, jj) * 10 + col] : 0.f);
    }

    float b1v[4][4], b2v[4][4];   // bias at D rows: feature = mt*16+quad*4+r
    #pragma unroll
    for (int mt = 0; mt < 4; ++mt)
        #pragma unroll
        for (int r = 0; r < 4; ++r) {
            b1v[mt][r] = n1b[mt * 16 + quad * 4 + r];
            b2v[mt][r] = n2b[mt * 16 + quad * 4 + r];
        }
    float hbv[3][4];              // head idx = quad*4+r (valid <10)
    #pragma unroll
    for (int mt = 0; mt < 3; ++mt) {
        const float* bb = (mt == 0) ? mub : (mt == 1) ? sgb : alb;
        #pragma unroll
        for (int r = 0; r < 4; ++r) {
            const int k = quad * 4 + r;
            hbv[mt][r] = (k < 10) ? bb[k] : 0.f;
        }
    }

    // ---- encoder (R4-verified x32 path; wave wv owns t-tile wv) ----
    {
        short8v E2f[2];
        #pragma unroll
        for (int kb = 0; kb < 2; ++kb)
            #pragma unroll
            for (int jj = 0; jj < 8; ++jj)
                E2f[kb][jj] = (short)bfr(col < 8 ? e2w[(kb * 32 + quad * 8 + jj) * 8 + col] : 0.f);
        short8v E1f[4];   // rank-1 layer: only k==0 nonzero
        #pragma unroll
        for (int nc = 0; nc < 4; ++nc)
            #pragma unroll
            for (int jj = 0; jj < 8; ++jj)
                E1f[nc][jj] = (short)((quad == 0 && jj == 0) ? bfr(e1w[nc * 16 + col]) : 0);
        float e1bv[4];
        #pragma unroll
        for (int nc = 0; nc < 4; ++nc) e1bv[nc] = e1b[nc * 16 + col];
        const float e2bv = (col < 8) ? e2b[col] : 0.f;
        float* hsw = hs_l[wv];

        __syncthreads();   // x_l ready

        #pragma unroll 1
        for (int nn = 0; nn < 16; ++nn) {
            short8v a0;
            #pragma unroll
            for (int jj = 0; jj < 8; ++jj) a0[jj] = 0;
            if (quad == 0) a0[0] = (short)bfr(x_l[nn * 130 + wv * 16 + col]);
            f32x4 c0[4];
            #pragma unroll
            for (int nc = 0; nc < 4; ++nc) c0[nc] = MFMA32(a0, E1f[nc], z4);
            #pragma unroll
            for (int nc = 0; nc < 4; ++nc)
                #pragma unroll
                for (int reg = 0; reg < 4; ++reg)
                    hsw[(quad * 4 + reg) * 68 + nc * 16 + col] = fmaxf(c0[nc][reg] + e1bv[nc], 0.f);
            short8v af[2];
            #pragma unroll
            for (int kb = 0; kb < 2; ++kb) {
                const f32x4 lo = *(const f32x4*)&hsw[col * 68 + kb * 32 + quad * 8];
                const f32x4 hi = *(const f32x4*)&hsw[col * 68 + kb * 32 + quad * 8 + 4];
                #pragma unroll
                for (int jj = 0; jj < 4; ++jj) { af[kb][jj] = bft(lo[jj]); af[kb][jj + 4] = bft(hi[jj]); }
            }
            f32x4 d0 = MFMA32(af[0], E2f[0], z4);
            d0 = MFMA32(af[1], E2f[1], d0);
            if (col < 8) {
                #pragma unroll
                for (int reg = 0; reg < 4; ++reg)
                    enc_l[(wv * 16 + quad * 4 + reg) * 128 + nn * 8 + col] = bfr(ftanh(d0[reg] + e2bv));
            }
        }
    }
    __syncthreads();   // enc_l fully ready

    // ---- recurrence: activations as permuted B-frags, fully in-register ----
    short8v tmpB, thB;
    #pragma unroll
    for (int jj = 0; jj < 8; ++jj) {
        const float v = initw[fi(0, jj)];
        tmpB[jj] = (short)bfr(v);
        thB[jj]  = (short)bfr(ftanh(v));
    }
    float res2 = 0.f;
    const float CST = 0.91893853320467274f;
    const int t0 = CH_S[wv], CL = CH_L[wv];

    // tmp_t from tmp_{t-1} via enc[t-1]; D tile mt=2d+h, row jj=h*4+r in-lane
    auto advance = [&](int t, bool wantth) {
        const short8v e8 = *(const short8v*)&enc_l[(t - 1) * 128 + col * 8];
        float ev[8];
        #pragma unroll
        for (int d = 0; d < 8; ++d) ev[d] = bf2f((unsigned short)e8[d]);
        short8v ntmp, nth;
        #pragma unroll
        for (int h = 0; h < 2; ++h) {     // halves cap accumulator pressure at 8 f32x4
            f32x4 D[8];
            #pragma unroll
            for (int d = 0; d < 8; ++d) D[d] = MFMA32(A2f[2 * d + h], tmpB, z4);
            #pragma unroll
            for (int r = 0; r < 4; ++r) {
                float s = 0.f;
                #pragma unroll
                for (int d = 0; d < 8; ++d) s = fmaf(ev[d], D[d][r], s);
                ntmp[h * 4 + r] = bft(s);
                if (wantth) nth[h * 4 + r] = bft(ftanh(s));
            }
        }
        tmpB = ntmp;
        if (wantth) thB = nth;
    };

    // cheap prefix to chunk start
    #pragma unroll 1
    for (int t = 1; t <= t0; ++t) advance(t, t == t0);

    // full steps in chunk — phi entirely in registers
    #pragma unroll 1
    for (int s = 0; s < CL; ++s) {
        const int t = t0 + s;
        if (s > 0) advance(t, true);

        // h1 = relu(W1^T @ th + b1), repacked in-lane to B-frag (jj=(mt&1)*4+r)
        short8v h1B[2];
        #pragma unroll
        for (int mt = 0; mt < 4; ++mt) {
            f32x4 d = MFMA32(W1f[mt], thB, z4);
            #pragma unroll
            for (int r = 0; r < 4; ++r)
                h1B[mt >> 1][(mt & 1) * 4 + r] = bft(fmaxf(d[r] + b1v[mt][r], 0.f));
        }
        // h2 = relu(W2^T @ h1 + b2)
        short8v h2B[2];
        #pragma unroll
        for (int mt = 0; mt < 4; ++mt) {
            f32x4 d = MFMA32(W2f[mt][0], h1B[0], z4);
            d = MFMA32(W2f[mt][1], h1B[1], d);
            #pragma unroll
            for (int r = 0; r < 4; ++r)
                h2B[mt >> 1][(mt & 1) * 4 + r] = bft(fmaxf(d[r] + b2v[mt][r], 0.f));
        }
        // heads: lane holds heads quad*4+r for sample col
        f32x4 hd[3];
        #pragma unroll
        for (int mt = 0; mt < 3; ++mt) {
            f32x4 d = MFMA32(Whf[mt][0], h2B[0], z4);
            d = MFMA32(Whf[mt][1], h2B[1], d);
            #pragma unroll
            for (int r = 0; r < 4; ++r) hd[mt][r] = d[r] + hbv[mt][r];
        }
        // epilogue: in-lane triplets, 2-shuffle cross-quad reduction.
        // no-max logsumexp: terms O(1); underflow -> 0 == reference's 0.
        const float xt = x_l[col * 130 + t];
        float s1 = 0.f, s2 = 0.f;
        #pragma unroll
        for (int r = 0; r < 4; ++r) {
            const bool valid = (quad * 4 + r) < 10;
            const float mu = hd[0][r], sg = hd[1][r], la = hd[2][r];
            const float e1t = __expf(la);
            const float z = (xt - mu) * __expf(-sg);
            const float e2t = __expf(la - sg - fmaf(0.5f * z, z, CST));
            s1 += valid ? e1t : 0.f;
            s2 += valid ? e2t : 0.f;
        }
        s1 += __shfl_xor(s1, 16, 64);  s2 += __shfl_xor(s2, 16, 64);
        s1 += __shfl_xor(s1, 32, 64);  s2 += __shfl_xor(s2, 32, 64);
        res2 += __log2f(s2) - __log2f(s1);
    }

    if (lane < 16) part_l[wv][lane] = res2;   // uniform across quads post-reduction
    __syncthreads();
    if (tid < 16) {
        float s = 0.f;
        #pragma unroll
        for (int w = 0; w < 8; ++w) s += part_l[w][tid];
        out[n0 + tid] = exp2f(s);
    }
}

extern "C" void kernel_launch(void* const* d_in, const int* in_sizes, int n_in,
                              void* d_out, int out_size, void* d_ws, size_t ws_size,
                              hipStream_t stream) {
    wfa_kernel<<<dim3(NN / 16), dim3(512), 0, stream>>>(
        (const float*)d_in[0],  (const float*)d_in[1],  (const float*)d_in[2],
        (const float*)d_in[3],  (const float*)d_in[4],  (const float*)d_in[5],
        (const float*)d_in[6],  (const float*)d_in[7],  (const float*)d_in[8],
        (const float*)d_in[9],  (const float*)d_in[10], (const float*)d_in[11],
        (const float*)d_in[12], (const float*)d_in[13], (const float*)d_in[14],
        (const float*)d_in[15], (const float*)d_in[16], (float*)d_out);
}

// Round 7
// 183.841 us; speedup vs baseline: 1.0851x; 1.0851x over previous
//
#include <hip/hip_runtime.h>

#define DEV __device__ __forceinline__

typedef __attribute__((ext_vector_type(8))) short short8v;
typedef __attribute__((ext_vector_type(4))) float f32x4;

DEV unsigned short bfr(float f) {                 // fp32 -> bf16 RNE (weights)
    unsigned u = __float_as_uint(f);
    return (unsigned short)((u + 0x7fffu + ((u >> 16) & 1u)) >> 16);
}
DEV short bft(float f) { return (short)(__float_as_uint(f) >> 16); } // truncate (activations)
DEV float bf2f(unsigned short h) { return __uint_as_float(((unsigned)h) << 16); }
DEV float frcp(float x) { return __builtin_amdgcn_rcpf(x); }
DEV float ftanh(float x) { float e = __expf(2.0f * x); return 1.0f - 2.0f * frcp(e + 1.0f); }

constexpr int NN = 4096, TT = 128;
#define MFMA32(a, b, c) __builtin_amdgcn_mfma_f32_16x16x32_bf16(a, b, c, 0, 0, 0)

// Permuted-feature in-lane chaining (verified R6): B slot k=quad*8+jj carries
// feature fi = (jj>>2)*16 + quad*4 + (jj&3); D rows (quad*4+r) repack to the
// next B operand in-lane. Only A2f (64 VGPR) is register-resident; W1/W2/Wh
// fragments live in ONE shared LDS copy (identical per lane across waves) and
// are streamed per full step; biases are the MFMA C operand read from LDS.

__constant__ const int CH_S[8] = {0, 44, 74, 94, 107, 116, 122, 126};
__constant__ const int CH_L[8] = {44, 30, 20, 13, 9, 6, 4, 2};

__global__ __launch_bounds__(512, 4) void wfa_kernel(
    const float* __restrict__ x,
    const float* __restrict__ e1w, const float* __restrict__ e1b,
    const float* __restrict__ e2w, const float* __restrict__ e2b,
    const float* __restrict__ A,
    const float* __restrict__ initw,
    const float* __restrict__ n1w, const float* __restrict__ n1b,
    const float* __restrict__ n2w, const float* __restrict__ n2b,
    const float* __restrict__ muw, const float* __restrict__ mub,
    const float* __restrict__ sgw, const float* __restrict__ sgb,
    const float* __restrict__ alw, const float* __restrict__ alb,
    float* __restrict__ out)
{
    __shared__ __align__(16) unsigned short enc_l[TT * 128];  // [t][n*8+d] bf16, 32KB
    __shared__ __align__(16) float x_l[16 * 130];             // [n][t]
    __shared__ __align__(16) short8v wfrag_l[18][64];         // W1(0-3) W2(4-11) Wh(12-17)
    __shared__ __align__(16) float n1b_l[64], n2b_l[64], hb_l[48];
    __shared__ float part_l[8][16];

    const int tid = threadIdx.x;
    const int wv = tid >> 6, lane = tid & 63;
    const int quad = lane >> 4, col = lane & 15;
    const int n0 = blockIdx.x * 16;
    const f32x4 z4 = {0.f, 0.f, 0.f, 0.f};

    // permuted input-feature index for B/k-slots
    auto fi = [&](int kc, int jj) { return kc * 32 + (jj >> 2) * 16 + quad * 4 + (jj & 3); };

    // ---- stage x ----
    for (int i = tid; i < 16 * TT; i += 512)
        x_l[(i >> 7) * 130 + (i & 127)] = x[(n0 + (i >> 7)) * TT + (i & 127)];

    // ---- shared weight-fragment LDS copy (wave w builds groups g%8==w) ----
    for (int g = wv; g < 18; g += 8) {
        short8v v;
        if (g < 4) {
            #pragma unroll
            for (int jj = 0; jj < 8; ++jj) v[jj] = (short)bfr(n1w[fi(0, jj) * 64 + g * 16 + col]);
        } else if (g < 12) {
            const int mt = (g - 4) >> 1, kb = (g - 4) & 1;
            #pragma unroll
            for (int jj = 0; jj < 8; ++jj) v[jj] = (short)bfr(n2w[fi(kb, jj) * 64 + mt * 16 + col]);
        } else {
            const int mt = (g - 12) >> 1, kb = (g - 12) & 1;
            const float* Wh = (mt == 0) ? muw : (mt == 1) ? sgw : alw;
            #pragma unroll
            for (int jj = 0; jj < 8; ++jj)
                v[jj] = (short)(col < 10 ? bfr(Wh[fi(kb, jj) * 10 + col]) : 0);
        }
        wfrag_l[g][lane] = v;
    }
    if (tid < 64) { n1b_l[tid] = n1b[tid]; n2b_l[tid] = n2b[tid]; }
    if (tid >= 64 && tid < 112) {
        const int i = tid - 64, mt = i >> 4, k = i & 15;
        hb_l[i] = (k < 10) ? ((mt == 0) ? mub[k] : (mt == 1) ? sgb[k] : alb[k]) : 0.f;
    }

    // ---- A2f: the only register-resident fragment set (64 VGPR) ----
    short8v A2f[16];   // out m = mt*16+col -> d=mt>>1, j=(mt&1)*16+col; k=i
    #pragma unroll
    for (int mt = 0; mt < 16; ++mt)
        #pragma unroll
        for (int jj = 0; jj < 8; ++jj)
            A2f[mt][jj] = (short)bfr(A[fi(0, jj) * 256 + (mt >> 1) * 32 + (mt & 1) * 16 + col]);

    __syncthreads();   // x_l ready (encoder); wfrag/bias done before 2nd sync

    // ---- encoder: in-lane rank-1 layer1 + 2 MFMAs; wave wv owns t-tile wv ----
    {
        float e1c[16], e1bc[16];
        #pragma unroll
        for (int kc = 0; kc < 2; ++kc)
            #pragma unroll
            for (int jj = 0; jj < 8; ++jj) {
                e1c[kc * 8 + jj] = e1w[fi(kc, jj)];
                e1bc[kc * 8 + jj] = e1b[fi(kc, jj)];
            }
        short8v E2A[2];   // A[m=d(col<8)][k=h feature, permuted]
        #pragma unroll
        for (int kc = 0; kc < 2; ++kc)
            #pragma unroll
            for (int jj = 0; jj < 8; ++jj)
                E2A[kc][jj] = (short)(col < 8 ? bfr(e2w[fi(kc, jj) * 8 + col]) : 0);
        float e2bc[4];
        #pragma unroll
        for (int r = 0; r < 4; ++r) e2bc[r] = (quad < 2) ? e2b[quad * 4 + r] : 0.f;

        const int tbase = wv * 16;
        #pragma unroll 1
        for (int nn = 0; nn < 16; ++nn) {
            const float xs = x_l[nn * 130 + tbase + col];
            short8v eB[2];
            #pragma unroll
            for (int kc = 0; kc < 2; ++kc)
                #pragma unroll
                for (int jj = 0; jj < 8; ++jj)
                    eB[kc][jj] = bft(fmaxf(fmaf(xs, e1c[kc * 8 + jj], e1bc[kc * 8 + jj]), 0.f));
            f32x4 d = MFMA32(E2A[0], eB[0], z4);
            d = MFMA32(E2A[1], eB[1], d);
            if (quad < 2) {
                #pragma unroll
                for (int r = 0; r < 4; ++r)
                    enc_l[(tbase + col) * 128 + nn * 8 + quad * 4 + r] = bfr(ftanh(d[r] + e2bc[r]));
            }
        }
    }
    __syncthreads();   // enc_l + wfrag_l + biases ready

    // ---- recurrence ----
    short8v tmpB, thB;
    #pragma unroll
    for (int jj = 0; jj < 8; ++jj) {
        const float v = initw[fi(0, jj)];
        tmpB[jj] = (short)bfr(v);
        thB[jj]  = (short)bfr(ftanh(v));
    }
    float res2 = 0.f;
    const float CST = 0.91893853320467274f;
    const int t0 = CH_S[wv], CL = CH_L[wv];

    auto advance = [&](int t, bool wantth) {
        const short8v e8 = *(const short8v*)&enc_l[(t - 1) * 128 + col * 8];
        float ev[8];
        #pragma unroll
        for (int d = 0; d < 8; ++d) ev[d] = bf2f((unsigned short)e8[d]);
        short8v ntmp, nth;
        #pragma unroll
        for (int h = 0; h < 2; ++h) {
            f32x4 D[8];
            #pragma unroll
            for (int d = 0; d < 8; ++d) D[d] = MFMA32(A2f[2 * d + h], tmpB, z4);
            #pragma unroll
            for (int r = 0; r < 4; ++r) {
                float s = 0.f;
                #pragma unroll
                for (int d = 0; d < 8; ++d) s = fmaf(ev[d], D[d][r], s);
                ntmp[h * 4 + r] = bft(s);
                if (wantth) nth[h * 4 + r] = bft(ftanh(s));
            }
        }
        tmpB = ntmp;
        if (wantth) thB = nth;
    };

    // cheap prefix to chunk start
    #pragma unroll 1
    for (int t = 1; t <= t0; ++t) advance(t, t == t0);

    // full steps: frags streamed from LDS each step (clobber blocks LICM)
    #pragma unroll 1
    for (int s = 0; s < CL; ++s) {
        const int t = t0 + s;
        asm volatile("" ::: "memory");

        short8v w1a[4];   // issue early: advance's ~300cyc hides the DS latency
        #pragma unroll
        for (int mt = 0; mt < 4; ++mt) w1a[mt] = wfrag_l[mt][lane];

        if (s > 0) advance(t, true);

        // h1 = relu(W1^T @ th + b1)   (bias as C operand)
        short8v h1B[2];
        #pragma unroll
        for (int mt = 0; mt < 4; ++mt) {
            const f32x4 c = *(const f32x4*)&n1b_l[mt * 16 + quad * 4];
            const f32x4 d = MFMA32(w1a[mt], thB, c);
            #pragma unroll
            for (int r = 0; r < 4; ++r)
                h1B[mt >> 1][(mt & 1) * 4 + r] = bft(fmaxf(d[r], 0.f));
        }
        // h2 = relu(W2^T @ h1 + b2)
        short8v h2B[2];
        #pragma unroll
        for (int mt = 0; mt < 4; ++mt) {
            const f32x4 c = *(const f32x4*)&n2b_l[mt * 16 + quad * 4];
            f32x4 d = MFMA32(wfrag_l[4 + mt * 2][lane], h1B[0], c);
            d = MFMA32(wfrag_l[5 + mt * 2][lane], h1B[1], d);
            #pragma unroll
            for (int r = 0; r < 4; ++r)
                h2B[mt >> 1][(mt & 1) * 4 + r] = bft(fmaxf(d[r], 0.f));
        }
        // heads (mu, sig, alpha); lane holds heads quad*4+r for sample col
        f32x4 hd[3];
        #pragma unroll
        for (int mt = 0; mt < 3; ++mt) {
            const f32x4 c = *(const f32x4*)&hb_l[mt * 16 + quad * 4];
            f32x4 d = MFMA32(wfrag_l[12 + mt * 2][lane], h2B[0], c);
            hd[mt] = MFMA32(wfrag_l[13 + mt * 2][lane], h2B[1], d);
        }
        // epilogue: no-max logsumexp (terms O(1); underflow->0 == reference's 0)
        const float xt = x_l[col * 130 + t];
        float s1 = 0.f, s2 = 0.f;
        #pragma unroll
        for (int r = 0; r < 4; ++r) {
            const bool valid = (quad * 4 + r) < 10;
            const float mu = hd[0][r], sg = hd[1][r], la = hd[2][r];
            const float e1t = __expf(la);
            const float z = (xt - mu) * __expf(-sg);
            const float e2t = __expf(la - sg - fmaf(0.5f * z, z, CST));
            s1 += valid ? e1t : 0.f;
            s2 += valid ? e2t : 0.f;
        }
        s1 += __shfl_xor(s1, 16, 64);  s2 += __shfl_xor(s2, 16, 64);
        s1 += __shfl_xor(s1, 32, 64);  s2 += __shfl_xor(s2, 32, 64);
        res2 += __log2f(s2) - __log2f(s1);
    }

    if (lane < 16) part_l[wv][lane] = res2;   // uniform across quads post-reduction
    __syncthreads();
    if (tid < 16) {
        float s = 0.f;
        #pragma unroll
        for (int w = 0; w < 8; ++w) s += part_l[w][tid];
        out[n0 + tid] = exp2f(s);
    }
}

extern "C" void kernel_launch(void* const* d_in, const int* in_sizes, int n_in,
                              void* d_out, int out_size, void* d_ws, size_t ws_size,
                              hipStream_t stream) {
    wfa_kernel<<<dim3(NN / 16), dim3(512), 0, stream>>>(
        (const float*)d_in[0],  (const float*)d_in[1],  (const float*)d_in[2],
        (const float*)d_in[3],  (const float*)d_in[4],  (const float*)d_in[5],
        (const float*)d_in[6],  (const float*)d_in[7],  (const float*)d_in[8],
        (const float*)d_in[9],  (const float*)d_in[10], (const float*)d_in[11],
        (const float*)d_in[12], (const float*)d_in[13], (const float*)d_in[14],
        (const float*)d_in[15], (const float*)d_in[16], (float*)d_out);
}

// Round 8
// 166.911 us; speedup vs baseline: 1.1952x; 1.1014x over previous
//
#include <hip/hip_runtime.h>

#define DEV __device__ __forceinline__

typedef __attribute__((ext_vector_type(8))) short short8v;
typedef __attribute__((ext_vector_type(4))) float f32x4;

DEV unsigned short bfr(float f) {                 // fp32 -> bf16 RNE (weights)
    unsigned u = __float_as_uint(f);
    return (unsigned short)((u + 0x7fffu + ((u >> 16) & 1u)) >> 16);
}
DEV short bft(float f) { return (short)(__float_as_uint(f) >> 16); } // truncate (activations)
DEV float bf2f(unsigned short h) { return __uint_as_float(((unsigned)h) << 16); }
DEV float frcp(float x) { return __builtin_amdgcn_rcpf(x); }
DEV float ftanh(float x) { float e = __expf(2.0f * x); return 1.0f - 2.0f * frcp(e + 1.0f); }

constexpr int NN = 4096, TT = 128;
#define MFMA32(a, b, c) __builtin_amdgcn_mfma_f32_16x16x32_bf16(a, b, c, 0, 0, 0)

// Permuted-feature in-lane chaining (verified R6/R7): B slot k=quad*8+jj
// carries feature (jj>>2)*16 + quad*4 + (jj&3); D rows (quad*4+r) repack into
// the next B operand fully in-lane. NO LAMBDAS / NO memory clobbers in this
// version: R4-R7's ~55MB "spill" is hypothesized to be lambda-capture +
// asm-memory-clobber defeating SROA (arrays stuck in scratch).

__constant__ const int CH_S[8] = {0, 44, 74, 94, 107, 116, 122, 126};
__constant__ const int CH_L[8] = {44, 30, 20, 13, 9, 6, 4, 2};

// tmp_t from tmp_{t-1} via enc[t-1]; expanded inline (no lambda!)
#define ADVANCE(T_, WANT_) do {                                               \
    const short8v e8_ = *(const short8v*)&enc_l[((T_) - 1) * 128 + col * 8];  \
    float ev_[8];                                                             \
    _Pragma("unroll")                                                         \
    for (int d_ = 0; d_ < 8; ++d_) ev_[d_] = bf2f((unsigned short)e8_[d_]);   \
    short8v ntmp_ = tmpB, nth_ = thB;                                         \
    _Pragma("unroll")                                                         \
    for (int h_ = 0; h_ < 2; ++h_) {                                          \
        f32x4 D_[8];                                                          \
        _Pragma("unroll")                                                     \
        for (int d_ = 0; d_ < 8; ++d_) D_[d_] = MFMA32(A2f[2 * d_ + h_], tmpB, z4); \
        _Pragma("unroll")                                                     \
        for (int r_ = 0; r_ < 4; ++r_) {                                      \
            float s_ = 0.f;                                                   \
            _Pragma("unroll")                                                 \
            for (int d_ = 0; d_ < 8; ++d_) s_ = fmaf(ev_[d_], D_[d_][r_], s_);\
            ntmp_[h_ * 4 + r_] = bft(s_);                                     \
            if (WANT_) nth_[h_ * 4 + r_] = bft(ftanh(s_));                    \
        }                                                                     \
    }                                                                         \
    tmpB = ntmp_;                                                             \
    if (WANT_) thB = nth_;                                                    \
} while (0)

__global__ __launch_bounds__(512) __attribute__((amdgpu_waves_per_eu(2)))
void wfa_kernel(
    const float* __restrict__ x,
    const float* __restrict__ e1w, const float* __restrict__ e1b,
    const float* __restrict__ e2w, const float* __restrict__ e2b,
    const float* __restrict__ A,
    const float* __restrict__ initw,
    const float* __restrict__ n1w, const float* __restrict__ n1b,
    const float* __restrict__ n2w, const float* __restrict__ n2b,
    const float* __restrict__ muw, const float* __restrict__ mub,
    const float* __restrict__ sgw, const float* __restrict__ sgb,
    const float* __restrict__ alw, const float* __restrict__ alb,
    float* __restrict__ out)
{
    __shared__ __align__(16) unsigned short enc_l[TT * 128];  // [t][n*8+d] bf16, 32KB
    __shared__ __align__(16) float x_l[16 * 130];             // [n][t]
    __shared__ __align__(16) short8v wfrag_l[18][64];         // W1(0-3) W2(4-11) Wh(12-17)
    __shared__ __align__(16) float n1b_l[64], n2b_l[64], hb_l[48];
    __shared__ float part_l[8][16];

    const int tid = threadIdx.x;
    const int wv = tid >> 6, lane = tid & 63;
    const int quad = lane >> 4, col = lane & 15;
    const int n0 = blockIdx.x * 16;
    const f32x4 z4 = {0.f, 0.f, 0.f, 0.f};

    // ---- stage x ----
    for (int i = tid; i < 16 * TT; i += 512)
        x_l[(i >> 7) * 130 + (i & 127)] = x[(n0 + (i >> 7)) * TT + (i & 127)];

    // ---- shared weight-fragment LDS copy (wave w builds groups g%8==w) ----
    for (int g = wv; g < 18; g += 8) {
        short8v v;
        if (g < 4) {
            #pragma unroll
            for (int jj = 0; jj < 8; ++jj)
                v[jj] = (short)bfr(n1w[((jj >> 2) * 16 + quad * 4 + (jj & 3)) * 64 + g * 16 + col]);
        } else if (g < 12) {
            const int mt = (g - 4) >> 1, kb = (g - 4) & 1;
            #pragma unroll
            for (int jj = 0; jj < 8; ++jj)
                v[jj] = (short)bfr(n2w[(kb * 32 + (jj >> 2) * 16 + quad * 4 + (jj & 3)) * 64 + mt * 16 + col]);
        } else {
            const int mt = (g - 12) >> 1, kb = (g - 12) & 1;
            const float* Wh = (mt == 0) ? muw : (mt == 1) ? sgw : alw;
            #pragma unroll
            for (int jj = 0; jj < 8; ++jj)
                v[jj] = (short)(col < 10
                    ? bfr(Wh[(kb * 32 + (jj >> 2) * 16 + quad * 4 + (jj & 3)) * 10 + col]) : 0);
        }
        wfrag_l[g][lane] = v;
    }
    if (tid < 64) { n1b_l[tid] = n1b[tid]; n2b_l[tid] = n2b[tid]; }
    if (tid >= 64 && tid < 112) {
        const int i = tid - 64, mt = i >> 4, k = i & 15;
        hb_l[i] = (k < 10) ? ((mt == 0) ? mub[k] : (mt == 1) ? sgb[k] : alb[k]) : 0.f;
    }

    // ---- A2f: register-resident contraction fragments (64 VGPR) ----
    short8v A2f[16];   // out m = mt*16+col -> d=mt>>1, j=(mt&1)*16+col; k=i (permuted)
    #pragma unroll
    for (int mt = 0; mt < 16; ++mt)
        #pragma unroll
        for (int jj = 0; jj < 8; ++jj)
            A2f[mt][jj] = (short)bfr(
                A[((jj >> 2) * 16 + quad * 4 + (jj & 3)) * 256 + (mt >> 1) * 32 + (mt & 1) * 16 + col]);

    __syncthreads();   // x_l ready

    // ---- encoder: in-lane rank-1 layer1 + 2 MFMAs; wave wv owns t-tile wv ----
    {
        float e1c[16], e1bc[16];
        #pragma unroll
        for (int kc = 0; kc < 2; ++kc)
            #pragma unroll
            for (int jj = 0; jj < 8; ++jj) {
                const int f = kc * 32 + (jj >> 2) * 16 + quad * 4 + (jj & 3);
                e1c[kc * 8 + jj] = e1w[f];
                e1bc[kc * 8 + jj] = e1b[f];
            }
        short8v E2A[2];   // A[m=d(col<8)][k=h feature, permuted]
        #pragma unroll
        for (int kc = 0; kc < 2; ++kc)
            #pragma unroll
            for (int jj = 0; jj < 8; ++jj)
                E2A[kc][jj] = (short)(col < 8
                    ? bfr(e2w[(kc * 32 + (jj >> 2) * 16 + quad * 4 + (jj & 3)) * 8 + col]) : 0);
        float e2bc[4];
        #pragma unroll
        for (int r = 0; r < 4; ++r) e2bc[r] = (quad < 2) ? e2b[quad * 4 + r] : 0.f;

        const int tbase = wv * 16;
        #pragma unroll 1
        for (int nn = 0; nn < 16; ++nn) {
            const float xs = x_l[nn * 130 + tbase + col];
            short8v eB[2];
            #pragma unroll
            for (int kc = 0; kc < 2; ++kc)
                #pragma unroll
                for (int jj = 0; jj < 8; ++jj)
                    eB[kc][jj] = bft(fmaxf(fmaf(xs, e1c[kc * 8 + jj], e1bc[kc * 8 + jj]), 0.f));
            f32x4 d = MFMA32(E2A[0], eB[0], z4);
            d = MFMA32(E2A[1], eB[1], d);
            if (quad < 2) {
                #pragma unroll
                for (int r = 0; r < 4; ++r)
                    enc_l[(tbase + col) * 128 + nn * 8 + quad * 4 + r] = bfr(ftanh(d[r] + e2bc[r]));
            }
        }
    }
    __syncthreads();   // enc_l + wfrag_l + biases ready

    // ---- recurrence ----
    short8v tmpB, thB;
    #pragma unroll
    for (int jj = 0; jj < 8; ++jj) {
        const float v = initw[(jj >> 2) * 16 + quad * 4 + (jj & 3)];
        tmpB[jj] = (short)bfr(v);
        thB[jj]  = (short)bfr(ftanh(v));
    }
    float res2 = 0.f;
    const float CST = 0.91893853320467274f;
    const int t0 = CH_S[wv], CL = CH_L[wv];

    // cheap prefix to chunk start (tanh only at the handoff step)
    #pragma unroll 1
    for (int t = 1; t < t0; ++t) ADVANCE(t, false);
    if (t0 > 0) ADVANCE(t0, true);

    // laundered byte-offset: blocks LICM of the wfrag LDS reads without any
    // memory clobber (register-only constraint -> cannot force stack traffic)
    unsigned wofs = (unsigned)(lane * sizeof(short8v));

    // full steps in chunk
    #pragma unroll 1
    for (int s = 0; s < CL; ++s) {
        const int t = t0 + s;
        asm volatile("" : "+v"(wofs));
        const char* wb = (const char*)&wfrag_l[0][0] + wofs;

        short8v w1a[4];   // issue early: ADVANCE's latency hides the DS reads
        #pragma unroll
        for (int mt = 0; mt < 4; ++mt) w1a[mt] = *(const short8v*)(wb + mt * 1024);

        if (s > 0) ADVANCE(t, true);

        // h1 = relu(W1^T @ th + b1)   (bias as C operand)
        short8v h1B[2];
        #pragma unroll
        for (int mt = 0; mt < 4; ++mt) {
            const f32x4 c = *(const f32x4*)&n1b_l[mt * 16 + quad * 4];
            const f32x4 d = MFMA32(w1a[mt], thB, c);
            #pragma unroll
            for (int r = 0; r < 4; ++r)
                h1B[mt >> 1][(mt & 1) * 4 + r] = bft(fmaxf(d[r], 0.f));
        }
        // h2 = relu(W2^T @ h1 + b2)
        short8v h2B[2];
        #pragma unroll
        for (int mt = 0; mt < 4; ++mt) {
            const f32x4 c = *(const f32x4*)&n2b_l[mt * 16 + quad * 4];
            f32x4 d = MFMA32(*(const short8v*)(wb + (4 + mt * 2) * 1024), h1B[0], c);
            d = MFMA32(*(const short8v*)(wb + (5 + mt * 2) * 1024), h1B[1], d);
            #pragma unroll
            for (int r = 0; r < 4; ++r)
                h2B[mt >> 1][(mt & 1) * 4 + r] = bft(fmaxf(d[r], 0.f));
        }
        // heads (mu, sig, alpha); lane holds heads quad*4+r for sample col
        f32x4 hd[3];
        #pragma unroll
        for (int mt = 0; mt < 3; ++mt) {
            const f32x4 c = *(const f32x4*)&hb_l[mt * 16 + quad * 4];
            f32x4 d = MFMA32(*(const short8v*)(wb + (12 + mt * 2) * 1024), h2B[0], c);
            hd[mt] = MFMA32(*(const short8v*)(wb + (13 + mt * 2) * 1024), h2B[1], d);
        }
        // epilogue: no-max logsumexp (terms O(1); underflow->0 == reference's 0)
        const float xt = x_l[col * 130 + t];
        float s1 = 0.f, s2 = 0.f;
        #pragma unroll
        for (int r = 0; r < 4; ++r) {
            const bool valid = (quad * 4 + r) < 10;
            const float mu = hd[0][r], sg = hd[1][r], la = hd[2][r];
            const float e1t = __expf(la);
            const float z = (xt - mu) * __expf(-sg);
            const float e2t = __expf(la - sg - fmaf(0.5f * z, z, CST));
            s1 += valid ? e1t : 0.f;
            s2 += valid ? e2t : 0.f;
        }
        s1 += __shfl_xor(s1, 16, 64);  s2 += __shfl_xor(s2, 16, 64);
        s1 += __shfl_xor(s1, 32, 64);  s2 += __shfl_xor(s2, 32, 64);
        res2 += __log2f(s2) - __log2f(s1);
    }

    if (lane < 16) part_l[wv][lane] = res2;   // uniform across quads post-reduction
    __syncthreads();
    if (tid < 16) {
        float s = 0.f;
        #pragma unroll
        for (int w = 0; w < 8; ++w) s += part_l[w][tid];
        out[n0 + tid] = exp2f(s);
    }
}

extern "C" void kernel_launch(void* const* d_in, const int* in_sizes, int n_in,
                              void* d_out, int out_size, void* d_ws, size_t ws_size,
                              hipStream_t stream) {
    wfa_kernel<<<dim3(NN / 16), dim3(512), 0, stream>>>(
        (const float*)d_in[0],  (const float*)d_in[1],  (const float*)d_in[2],
        (const float*)d_in[3],  (const float*)d_in[4],  (const float*)d_in[5],
        (const float*)d_in[6],  (const float*)d_in[7],  (const float*)d_in[8],
        (const float*)d_in[9],  (const float*)d_in[10], (const float*)d_in[11],
        (const float*)d_in[12], (const float*)d_in[13], (const float*)d_in[14],
        (const float*)d_in[15], (const float*)d_in[16], (float*)d_out);
}

// Round 9
// 141.114 us; speedup vs baseline: 1.4136x; 1.1828x over previous
//
#include <hip/hip_runtime.h>

#define DEV __device__ __forceinline__

typedef __attribute__((ext_vector_type(8))) short short8v;
typedef __attribute__((ext_vector_type(4))) float f32x4;

DEV unsigned short bfr(float f) {                 // fp32 -> bf16 RNE (weights)
    unsigned u = __float_as_uint(f);
    return (unsigned short)((u + 0x7fffu + ((u >> 16) & 1u)) >> 16);
}
DEV short bft(float f) { return (short)(__float_as_uint(f) >> 16); } // truncate (activations)
DEV float bf2f(unsigned short h) { return __uint_as_float(((unsigned)h) << 16); }
DEV float frcp(float x) { return __builtin_amdgcn_rcpf(x); }
DEV float ftanh(float x) { float e = __expf(2.0f * x); return 1.0f - 2.0f * frcp(e + 1.0f); }

constexpr int NN = 4096, TT = 128;
#define MFMA32(a, b, c) __builtin_amdgcn_mfma_f32_16x16x32_bf16(a, b, c, 0, 0, 0)

// Producer/consumer wave specialization. Wave 0 (scanner) runs ONLY the serial
// tmp recurrence (127 advances, no tanh/phi) and publishes the bf16 tmp B-frag
// to a double-buffered LDS ring in batches of 8. Waves 1-7 (consumers) hold
// the phi weight fragments in registers and consume batch b-1 while batch b is
// produced. Single __syncthreads site per batch iteration (uniform control).
// Permuted-feature in-lane chaining as R6-R8: B slot k=quad*8+jj carries
// feature (jj>>2)*16+quad*4+(jj&3); D rows quad*4+r repack in-lane.
// NO lambdas / NO asm memory clobbers (R8 lesson: they caused 35-64MB scratch).

__global__ __launch_bounds__(512) __attribute__((amdgpu_waves_per_eu(2)))
void wfa_kernel(
    const float* __restrict__ x,
    const float* __restrict__ e1w, const float* __restrict__ e1b,
    const float* __restrict__ e2w, const float* __restrict__ e2b,
    const float* __restrict__ A,
    const float* __restrict__ initw,
    const float* __restrict__ n1w, const float* __restrict__ n1b,
    const float* __restrict__ n2w, const float* __restrict__ n2b,
    const float* __restrict__ muw, const float* __restrict__ mub,
    const float* __restrict__ sgw, const float* __restrict__ sgb,
    const float* __restrict__ alw, const float* __restrict__ alb,
    float* __restrict__ out)
{
    __shared__ __align__(16) unsigned short enc_l[TT * 128];  // [t][n*8+d] bf16, 32KB
    __shared__ __align__(16) float x_l[16 * 130];             // [n][t]
    __shared__ __align__(16) short8v ring_l[2][8][64];        // tmp frags, 16KB
    __shared__ __align__(16) float n1b_l[64], n2b_l[64], hb_l[48];
    __shared__ float part_l[8][16];

    const int tid = threadIdx.x;
    const int wv = tid >> 6, lane = tid & 63;
    const int quad = lane >> 4, col = lane & 15;
    const int n0 = blockIdx.x * 16;
    const f32x4 z4 = {0.f, 0.f, 0.f, 0.f};

    // ---- stage x ----
    for (int i = tid; i < 16 * TT; i += 512)
        x_l[(i >> 7) * 130 + (i & 127)] = x[(n0 + (i >> 7)) * TT + (i & 127)];
    if (tid < 64) { n1b_l[tid] = n1b[tid]; n2b_l[tid] = n2b[tid]; }
    if (tid >= 64 && tid < 112) {
        const int i = tid - 64, mt = i >> 4, k = i & 15;
        hb_l[i] = (k < 10) ? ((mt == 0) ? mub[k] : (mt == 1) ? sgb[k] : alb[k]) : 0.f;
    }

    __syncthreads();   // x_l ready

    // ---- encoder: in-lane rank-1 layer1 + 2 MFMAs; wave wv owns t-tile wv ----
    {
        float e1c[16], e1bc[16];
        #pragma unroll
        for (int kc = 0; kc < 2; ++kc)
            #pragma unroll
            for (int jj = 0; jj < 8; ++jj) {
                const int f = kc * 32 + (jj >> 2) * 16 + quad * 4 + (jj & 3);
                e1c[kc * 8 + jj] = e1w[f];
                e1bc[kc * 8 + jj] = e1b[f];
            }
        short8v E2A[2];   // A[m=d(col<8)][k=h feature, permuted]
        #pragma unroll
        for (int kc = 0; kc < 2; ++kc)
            #pragma unroll
            for (int jj = 0; jj < 8; ++jj)
                E2A[kc][jj] = (short)(col < 8
                    ? bfr(e2w[(kc * 32 + (jj >> 2) * 16 + quad * 4 + (jj & 3)) * 8 + col]) : 0);
        float e2bc[4];
        #pragma unroll
        for (int r = 0; r < 4; ++r) e2bc[r] = (quad < 2) ? e2b[quad * 4 + r] : 0.f;

        const int tbase = wv * 16;
        #pragma unroll 1
        for (int nn = 0; nn < 16; ++nn) {
            const float xs = x_l[nn * 130 + tbase + col];
            short8v eB[2];
            #pragma unroll
            for (int kc = 0; kc < 2; ++kc)
                #pragma unroll
                for (int jj = 0; jj < 8; ++jj)
                    eB[kc][jj] = bft(fmaxf(fmaf(xs, e1c[kc * 8 + jj], e1bc[kc * 8 + jj]), 0.f));
            f32x4 d = MFMA32(E2A[0], eB[0], z4);
            d = MFMA32(E2A[1], eB[1], d);
            if (quad < 2) {
                #pragma unroll
                for (int r = 0; r < 4; ++r)
                    enc_l[(tbase + col) * 128 + nn * 8 + quad * 4 + r] = bfr(ftanh(d[r] + e2bc[r]));
            }
        }
    }
    __syncthreads();   // enc_l ready

    if (wv == 0) {
        // =========================== SCANNER ===========================
        short8v A2f[16];   // out m=mt*16+col -> d=mt>>1, j-half=mt&1; k=i (permuted)
        #pragma unroll
        for (int mt = 0; mt < 16; ++mt)
            #pragma unroll
            for (int jj = 0; jj < 8; ++jj)
                A2f[mt][jj] = (short)bfr(
                    A[((jj >> 2) * 16 + quad * 4 + (jj & 3)) * 256 + (mt >> 1) * 32 + (mt & 1) * 16 + col]);

        short8v tmpB;
        #pragma unroll
        for (int jj = 0; jj < 8; ++jj)
            tmpB[jj] = (short)bfr(initw[(jj >> 2) * 16 + quad * 4 + (jj & 3)]);

        asm volatile("s_setprio 2");   // win SIMD arbitration vs co-resident consumer

        short8v e8c = *(const short8v*)&enc_l[0 * 128 + col * 8];  // enc[0] for t=1

        #pragma unroll 1
        for (int b = 0; b <= 16; ++b) {
            if (b < 16) {
                #pragma unroll 1
                for (int i = 0; i < 8; ++i) {
                    const int t = b * 8 + i;
                    if (t > 0) {
                        // prefetch enc[t] (used at t+1); waited only at e8c=e8n
                        const short8v e8n = *(const short8v*)&enc_l[t * 128 + col * 8];
                        float ev[8];
                        #pragma unroll
                        for (int d = 0; d < 8; ++d) ev[d] = bf2f((unsigned short)e8c[d]);
                        short8v nt;
                        #pragma unroll
                        for (int h = 0; h < 2; ++h) {
                            f32x4 D[8];
                            #pragma unroll
                            for (int d = 0; d < 8; ++d) D[d] = MFMA32(A2f[2 * d + h], tmpB, z4);
                            #pragma unroll
                            for (int r = 0; r < 4; ++r) {
                                float s = 0.f;
                                #pragma unroll
                                for (int d = 0; d < 8; ++d) s = fmaf(ev[d], D[d][r], s);
                                nt[h * 4 + r] = bft(s);
                            }
                        }
                        tmpB = nt;
                        e8c = e8n;
                    }
                    ring_l[b & 1][i][lane] = tmpB;
                }
            }
            __syncthreads();
        }
        if (lane < 16) part_l[0][lane] = 0.f;
    } else {
        // ========================== CONSUMERS ==========================
        short8v W1f[4];    // h1 out = mt*16+col, k = th feature (permuted)
        #pragma unroll
        for (int mt = 0; mt < 4; ++mt)
            #pragma unroll
            for (int jj = 0; jj < 8; ++jj)
                W1f[mt][jj] = (short)bfr(n1w[((jj >> 2) * 16 + quad * 4 + (jj & 3)) * 64 + mt * 16 + col]);
        short8v W2f[4][2];
        #pragma unroll
        for (int mt = 0; mt < 4; ++mt)
            #pragma unroll
            for (int kb = 0; kb < 2; ++kb)
                #pragma unroll
                for (int jj = 0; jj < 8; ++jj)
                    W2f[mt][kb][jj] = (short)bfr(
                        n2w[(kb * 32 + (jj >> 2) * 16 + quad * 4 + (jj & 3)) * 64 + mt * 16 + col]);
        short8v Whf[3][2]; // 0=mu,1=sig,2=alpha; out m = head idx (col<10)
        #pragma unroll
        for (int mt = 0; mt < 3; ++mt) {
            const float* Wh = (mt == 0) ? muw : (mt == 1) ? sgw : alw;
            #pragma unroll
            for (int kb = 0; kb < 2; ++kb)
                #pragma unroll
                for (int jj = 0; jj < 8; ++jj)
                    Whf[mt][kb][jj] = (short)(col < 10
                        ? bfr(Wh[(kb * 32 + (jj >> 2) * 16 + quad * 4 + (jj & 3)) * 10 + col]) : 0);
        }

        float res2 = 0.f;
        const float CST = 0.91893853320467274f;

        #pragma unroll 1
        for (int b = 0; b <= 16; ++b) {
            if (b >= 1) {
                #pragma unroll 1
                for (int i = wv - 1; i < 8; i += 7) {   // wv=1 takes i=0,7
                    const int t = (b - 1) * 8 + i;
                    const short8v tf = ring_l[(b - 1) & 1][i][lane];
                    short8v thB;
                    #pragma unroll
                    for (int jj = 0; jj < 8; ++jj)
                        thB[jj] = bft(ftanh(bf2f((unsigned short)tf[jj])));

                    // h1 = relu(W1^T @ th + b1)   (bias as C operand)
                    short8v h1B[2];
                    #pragma unroll
                    for (int mt = 0; mt < 4; ++mt) {
                        const f32x4 c = *(const f32x4*)&n1b_l[mt * 16 + quad * 4];
                        const f32x4 d = MFMA32(W1f[mt], thB, c);
                        #pragma unroll
                        for (int r = 0; r < 4; ++r)
                            h1B[mt >> 1][(mt & 1) * 4 + r] = bft(fmaxf(d[r], 0.f));
                    }
                    // h2 = relu(W2^T @ h1 + b2)
                    short8v h2B[2];
                    #pragma unroll
                    for (int mt = 0; mt < 4; ++mt) {
                        const f32x4 c = *(const f32x4*)&n2b_l[mt * 16 + quad * 4];
                        f32x4 d = MFMA32(W2f[mt][0], h1B[0], c);
                        d = MFMA32(W2f[mt][1], h1B[1], d);
                        #pragma unroll
                        for (int r = 0; r < 4; ++r)
                            h2B[mt >> 1][(mt & 1) * 4 + r] = bft(fmaxf(d[r], 0.f));
                    }
                    // heads; lane holds heads quad*4+r for sample col
                    f32x4 hd[3];
                    #pragma unroll
                    for (int mt = 0; mt < 3; ++mt) {
                        const f32x4 c = *(const f32x4*)&hb_l[mt * 16 + quad * 4];
                        f32x4 d = MFMA32(Whf[mt][0], h2B[0], c);
                        hd[mt] = MFMA32(Whf[mt][1], h2B[1], d);
                    }
                    // no-max logsumexp (terms O(1); underflow->0 == reference's 0)
                    const float xt = x_l[col * 130 + t];
                    float s1 = 0.f, s2 = 0.f;
                    #pragma unroll
                    for (int r = 0; r < 4; ++r) {
                        const bool valid = (quad * 4 + r) < 10;
                        const float mu = hd[0][r], sg = hd[1][r], la = hd[2][r];
                        const float e1t = __expf(la);
                        const float z = (xt - mu) * __expf(-sg);
                        const float e2t = __expf(la - sg - fmaf(0.5f * z, z, CST));
                        s1 += valid ? e1t : 0.f;
                        s2 += valid ? e2t : 0.f;
                    }
                    s1 += __shfl_xor(s1, 16, 64);  s2 += __shfl_xor(s2, 16, 64);
                    s1 += __shfl_xor(s1, 32, 64);  s2 += __shfl_xor(s2, 32, 64);
                    res2 += __log2f(s2) - __log2f(s1);
                }
            }
            __syncthreads();
        }
        if (lane < 16) part_l[wv][lane] = res2;   // uniform across quads
    }

    __syncthreads();
    if (tid < 16) {
        float s = 0.f;
        #pragma unroll
        for (int w = 0; w < 8; ++w) s += part_l[w][tid];
        out[n0 + tid] = exp2f(s);
    }
}

extern "C" void kernel_launch(void* const* d_in, const int* in_sizes, int n_in,
                              void* d_out, int out_size, void* d_ws, size_t ws_size,
                              hipStream_t stream) {
    wfa_kernel<<<dim3(NN / 16), dim3(512), 0, stream>>>(
        (const float*)d_in[0],  (const float*)d_in[1],  (const float*)d_in[2],
        (const float*)d_in[3],  (const float*)d_in[4],  (const float*)d_in[5],
        (const float*)d_in[6],  (const float*)d_in[7],  (const float*)d_in[8],
        (const float*)d_in[9],  (const float*)d_in[10], (const float*)d_in[11],
        (const float*)d_in[12], (const float*)d_in[13], (const float*)d_in[14],
        (const float*)d_in[15], (const float*)d_in[16], (float*)d_out);
}